// Round 1
// baseline (678.171 us; speedup 1.0000x reference)
//
#include <hip/hip_runtime.h>
#include <stdint.h>

typedef __attribute__((ext_vector_type(8))) __bf16 bf16x8;
typedef __attribute__((ext_vector_type(4))) float f32x4;

#define S_TOK 1024
#define H_DIM 768
#define NLBL  50
#define NEDGE 65536
#define NSEG  (S_TOK * NLBL)      // 51200
#define NSPAN 9171
#define MPAD  9216                // 72 * 128
#define DDIM  2304
#define KTOP  409
#define KGCN  (NLBL * H_DIM)      // 38400

__device__ __forceinline__ unsigned short f32_to_bf16u(float f) {
  unsigned u = __float_as_uint(f);
  u += 0x7fffu + ((u >> 16) & 1u);          // round-to-nearest-even
  return (unsigned short)(u >> 16);
}
__device__ __forceinline__ float bf16u_to_f32(unsigned short h) {
  return __uint_as_float(((unsigned)h) << 16);
}

// ---------------- transpose + fp32->bf16 convert: in (R x C) -> out (C x R) ----
__global__ __launch_bounds__(256) void transpose_conv(
    const float* __restrict__ in, unsigned short* __restrict__ out, int R, int C) {
  __shared__ float tile[32][33];
  int tx = threadIdx.x & 31, ty = threadIdx.x >> 5;   // 32 x 8
  int c0 = blockIdx.x * 32, r0 = blockIdx.y * 32;
#pragma unroll
  for (int i = 0; i < 4; i++)
    tile[ty + 8 * i][tx] = in[(size_t)(r0 + ty + 8 * i) * C + c0 + tx];
  __syncthreads();
#pragma unroll
  for (int i = 0; i < 4; i++)
    out[(size_t)(c0 + ty + 8 * i) * R + r0 + tx] = f32_to_bf16u(tile[tx][ty + 8 * i]);
}

// ---------------- edge bucketing ----------------
__global__ void edge_count(const int* __restrict__ edges, int* __restrict__ seg_count) {
  int e = blockIdx.x * 256 + threadIdx.x;
  if (e >= NEDGE) return;
  int tgt = edges[e * 3 + 1], lbl = edges[e * 3 + 2];
  atomicAdd(&seg_count[tgt * NLBL + lbl], 1);
}

__global__ __launch_bounds__(1024) void scan_kernel(
    const int* __restrict__ cnt, int* __restrict__ offs) {
  __shared__ int part[1024];
  int t = threadIdx.x;
  int base = t * 50;                    // 1024 * 50 = 51200
  int s = 0;
  for (int i = 0; i < 50; i++) s += cnt[base + i];
  part[t] = s;
  __syncthreads();
  for (int o = 1; o < 1024; o <<= 1) {
    int v = part[t];
    int u = (t >= o) ? part[t - o] : 0;
    __syncthreads();
    part[t] = v + u;
    __syncthreads();
  }
  int ex = part[t] - s;                 // exclusive base for this thread's range
  for (int i = 0; i < 50; i++) { offs[base + i] = ex; ex += cnt[base + i]; }
  if (t == 1023) offs[NSEG] = ex;       // total = NEDGE
}

__global__ void edge_scatter(const int* __restrict__ edges, const int* __restrict__ seg_off,
                             int* __restrict__ seg_cursor, int* __restrict__ sorted_src) {
  int e = blockIdx.x * 256 + threadIdx.x;
  if (e >= NEDGE) return;
  int src = edges[e * 3], tgt = edges[e * 3 + 1], lbl = edges[e * 3 + 2];
  int seg = tgt * NLBL + lbl;
  int pos = seg_off[seg] + atomicAdd(&seg_cursor[seg], 1);
  sorted_src[pos] = src;
}

// one wave per segment: agg[seg][h] = sum over edges of x[src][h], write bf16
__global__ __launch_bounds__(256) void agg_kernel(
    const float* __restrict__ x, const int* __restrict__ seg_off,
    const int* __restrict__ sorted_src, unsigned short* __restrict__ agg) {
  int wave = threadIdx.x >> 6, lane = threadIdx.x & 63;
  int seg = blockIdx.x * 4 + wave;
  int b = seg_off[seg], e = seg_off[seg + 1];
  float acc[12];
#pragma unroll
  for (int i = 0; i < 12; i++) acc[i] = 0.f;
  for (int p = b; p < e; p++) {
    const float* row = x + (size_t)sorted_src[p] * H_DIM;
#pragma unroll
    for (int i = 0; i < 12; i++) acc[i] += row[lane + 64 * i];
  }
  unsigned short* dst = agg + (size_t)seg * H_DIM;
#pragma unroll
  for (int i = 0; i < 12; i++) dst[lane + 64 * i] = f32_to_bf16u(acc[i]);
}

// ---------------- bf16 MFMA GEMM, 128x128 tile, BK=64 ----------------
// A: M x K row-major (lda=K), B: N x K row-major (ldb=K)  [B pre-transposed]
// EPI 0: split-K, atomicAdd fp32 into C (M x Nn)
// EPI 1: scores[m] += sum_n relu(acc + b1[n]) * w2[n]   (guard m < M)
template <int EPI>
__global__ __launch_bounds__(256) void gemm_bf16(
    const __bf16* __restrict__ A, const __bf16* __restrict__ B,
    float* __restrict__ C, const float* __restrict__ b1, const float* __restrict__ w2,
    int M, int Nn, int K, int mb, int nb, int kChunk) {
  __shared__ __bf16 As[128 * 72];
  __shared__ __bf16 Bs[128 * 72];
  int bid = blockIdx.x;
  int im = bid % mb; bid /= mb;
  int in_ = bid % nb; int ik = bid / nb;
  int m0 = im * 128, n0 = in_ * 128;
  int k0 = ik * kChunk, k1 = k0 + kChunk;

  int t = threadIdx.x;
  int wave = t >> 6, lane = t & 63;
  int wr = wave >> 1, wc = wave & 1;
  int quad = lane >> 4, l15 = lane & 15;

  f32x4 acc[4][4];
  f32x4 zero = {0.f, 0.f, 0.f, 0.f};
#pragma unroll
  for (int mi = 0; mi < 4; mi++)
#pragma unroll
    for (int ni = 0; ni < 4; ni++) acc[mi][ni] = zero;

  for (int kt = k0; kt < k1; kt += 64) {
#pragma unroll
    for (int i = 0; i < 4; i++) {
      int c = t + i * 256;                 // 1024 chunks of 8 bf16
      int row = c >> 3, k8 = (c & 7) << 3;
      *(bf16x8*)&As[row * 72 + k8] = *(const bf16x8*)(A + (size_t)(m0 + row) * K + kt + k8);
      *(bf16x8*)&Bs[row * 72 + k8] = *(const bf16x8*)(B + (size_t)(n0 + row) * K + kt + k8);
    }
    __syncthreads();
#pragma unroll
    for (int kk = 0; kk < 64; kk += 32) {
      bf16x8 af[4], bg[4];
#pragma unroll
      for (int mi = 0; mi < 4; mi++)
        af[mi] = *(const bf16x8*)&As[(wr * 64 + mi * 16 + l15) * 72 + kk + quad * 8];
#pragma unroll
      for (int ni = 0; ni < 4; ni++)
        bg[ni] = *(const bf16x8*)&Bs[(wc * 64 + ni * 16 + l15) * 72 + kk + quad * 8];
#pragma unroll
      for (int mi = 0; mi < 4; mi++)
#pragma unroll
        for (int ni = 0; ni < 4; ni++)
          acc[mi][ni] = __builtin_amdgcn_mfma_f32_16x16x32_bf16(af[mi], bg[ni], acc[mi][ni], 0, 0, 0);
    }
    __syncthreads();
  }

  if (EPI == 0) {
#pragma unroll
    for (int mi = 0; mi < 4; mi++) {
      int gm = m0 + wr * 64 + mi * 16 + quad * 4;
#pragma unroll
      for (int ni = 0; ni < 4; ni++) {
        int gn = n0 + wc * 64 + ni * 16 + l15;
#pragma unroll
        for (int r = 0; r < 4; r++)
          atomicAdd(&C[(size_t)(gm + r) * Nn + gn], acc[mi][ni][r]);
      }
    }
  } else {
    float b1v[4], w2v[4];
#pragma unroll
    for (int ni = 0; ni < 4; ni++) {
      int gn = n0 + wc * 64 + ni * 16 + l15;
      b1v[ni] = b1[gn];
      w2v[ni] = w2[gn];
    }
#pragma unroll
    for (int mi = 0; mi < 4; mi++) {
      int gm = m0 + wr * 64 + mi * 16 + quad * 4;
      float part[4] = {0.f, 0.f, 0.f, 0.f};
#pragma unroll
      for (int ni = 0; ni < 4; ni++)
#pragma unroll
        for (int r = 0; r < 4; r++)
          part[r] += fmaxf(acc[mi][ni][r] + b1v[ni], 0.f) * w2v[ni];
#pragma unroll
      for (int o = 1; o < 16; o <<= 1)
#pragma unroll
        for (int r = 0; r < 4; r++) part[r] += __shfl_xor(part[r], o, 64);
      if (l15 == 0) {
#pragma unroll
        for (int r = 0; r < 4; r++)
          if (gm + r < M) atomicAdd(&C[gm + r], part[r]);
      }
    }
  }
}

// ---------------- emb = x + relu((C1 + cnt@gcn_b)/degree) ----------------
__global__ __launch_bounds__(256) void emb_kernel(
    const float* __restrict__ x, const float* __restrict__ C1,
    const int* __restrict__ seg_count, const float* __restrict__ gcn_b,
    float* __restrict__ emb) {
  int s = blockIdx.x;
  __shared__ float cntf[NLBL];
  __shared__ float degs;
  int t = threadIdx.x;
  if (t < NLBL) cntf[t] = (float)seg_count[s * NLBL + t];
  __syncthreads();
  if (t == 0) {
    float d = 0.f;
    for (int l = 0; l < NLBL; l++) d += cntf[l];
    degs = fmaxf(d, 1.f);
  }
  __syncthreads();
  float dinv = 1.f / degs;
  for (int h = t; h < H_DIM; h += 256) {
    float bias = 0.f;
    for (int l = 0; l < NLBL; l++) bias += cntf[l] * gcn_b[l * H_DIM + h];
    float v = (C1[(size_t)s * H_DIM + h] + bias) * dinv;
    emb[(size_t)s * H_DIM + h] = x[(size_t)s * H_DIM + h] + fmaxf(v, 0.f);
  }
}

// ---------------- span attention + span_vec (bf16) ----------------
__global__ __launch_bounds__(256) void span_kernel(
    const float* __restrict__ emb, const int* __restrict__ starts,
    const int* __restrict__ ends, const float* __restrict__ attn_w,
    unsigned short* __restrict__ spanv, int nspan) {
  int n = blockIdx.x;
  if (n >= nspan) return;
  int start = starts[n], end = ends[n];
  int len = end - start + 1;            // 2..10
  __shared__ float sc[10];
  __shared__ float red[4];
  int t = threadIdx.x, lane = t & 63, wave = t >> 6;
  for (int w = 0; w < len; w++) {
    const float* row = emb + (size_t)(start + w) * H_DIM;
    float p = 0.f;
    for (int h = t; h < H_DIM; h += 256) p += row[h] * attn_w[h];
    for (int o = 32; o; o >>= 1) p += __shfl_down(p, o, 64);
    if (lane == 0) red[wave] = p;
    __syncthreads();
    if (t == 0) sc[w] = red[0] + red[1] + red[2] + red[3];
    __syncthreads();
  }
  float m = -1e30f;
  for (int w = 0; w < len; w++) m = fmaxf(m, sc[w]);
  float aw[10];
  float ssum = 0.f;
  for (int w = 0; w < len; w++) { aw[w] = __expf(sc[w] - m); ssum += aw[w]; }
  float inv = 1.f / ssum;
  const float* rs = emb + (size_t)start * H_DIM;
  const float* re = emb + (size_t)end * H_DIM;
  unsigned short* out = spanv + (size_t)n * DDIM;
  for (int h = t; h < H_DIM; h += 256) {
    float a = 0.f;
    for (int w = 0; w < len; w++) a += aw[w] * emb[(size_t)(start + w) * H_DIM + h];
    out[h] = f32_to_bf16u(rs[h]);
    out[H_DIM + h] = f32_to_bf16u(re[h]);
    out[2 * H_DIM + h] = f32_to_bf16u(a * inv);
  }
}

// ---------------- top-k (radix select + small bitonic), single block -------
__device__ __forceinline__ unsigned score_key(float s) {
  unsigned b = __float_as_uint(s);
  return (b & 0x80000000u) ? ~b : (b | 0x80000000u);   // ascending-order key
}

__global__ __launch_bounds__(1024) void topk_kernel(
    const float* __restrict__ scores, int* __restrict__ topk_idx) {
  __shared__ int hist[256];
  __shared__ unsigned sh_prefix;
  __shared__ int sh_remaining, sh_cnt;
  __shared__ unsigned long long keys[512];
  int t = threadIdx.x;
  unsigned prefix = 0;
  int remaining = KTOP;
  for (int p = 3; p >= 0; p--) {
    for (int b = t; b < 256; b += 1024) hist[b] = 0;
    __syncthreads();
    for (int i = t; i < NSPAN; i += 1024) {
      unsigned u = score_key(scores[i]);
      bool ok = (p == 3) ? true : ((u >> ((p + 1) * 8)) == prefix);
      if (ok) atomicAdd(&hist[(u >> (p * 8)) & 0xff], 1);
    }
    __syncthreads();
    if (t == 0) {
      int rem = remaining;
      int b = 255;
      for (;; b--) {
        int c = hist[b];
        if (c >= rem) break;
        rem -= c;
      }
      sh_prefix = (prefix << 8) | (unsigned)b;
      sh_remaining = rem;
    }
    __syncthreads();
    prefix = sh_prefix;
    remaining = sh_remaining;
    __syncthreads();
  }
  unsigned kth = prefix;
  if (t == 0) sh_cnt = 0;
  __syncthreads();
  for (int i = t; i < NSPAN; i += 1024) {
    unsigned u = score_key(scores[i]);
    if (u >= kth) {
      int pos = atomicAdd(&sh_cnt, 1);
      if (pos < 512) keys[pos] = (((unsigned long long)(~u)) << 32) | (unsigned)i;
    }
  }
  __syncthreads();
  int cnt = sh_cnt < 512 ? sh_cnt : 512;
  for (int i = t; i < 512; i += 1024)
    if (i >= cnt) keys[i] = ~0ull;
  __syncthreads();
  // bitonic sort 512 ascending: key = (~u, idx) -> score desc, idx asc
  for (int ksz = 2; ksz <= 512; ksz <<= 1)
    for (int j = ksz >> 1; j > 0; j >>= 1) {
      if (t < 512) {
        int ixj = t ^ j;
        if (ixj > t) {
          unsigned long long a = keys[t], b = keys[ixj];
          bool up = ((t & ksz) == 0);
          if (up ? (a > b) : (a < b)) { keys[t] = b; keys[ixj] = a; }
        }
      }
      __syncthreads();
    }
  for (int i = t; i < KTOP; i += 1024) topk_idx[i] = (int)(keys[i] & 0xffffffffu);
}

// ---------------- s_i / s_j for pruned spans ----------------
__global__ __launch_bounds__(256) void sij_kernel(
    const unsigned short* __restrict__ spanv, const int* __restrict__ topk_idx,
    const float* __restrict__ antW, float* __restrict__ s_i, float* __restrict__ s_j) {
  int r = blockIdx.x;
  int idx = topk_idx[r];
  const unsigned short* row = spanv + (size_t)idx * DDIM;
  int t = threadIdx.x, lane = t & 63, wave = t >> 6;
  float pi = 0.f, pj = 0.f;
  for (int d = t; d < DDIM; d += 256) {
    float v = bf16u_to_f32(row[d]);
    pi += v * antW[d];
    pj += v * antW[DDIM + d];
  }
  for (int o = 32; o; o >>= 1) {
    pi += __shfl_down(pi, o, 64);
    pj += __shfl_down(pj, o, 64);
  }
  __shared__ float ri[4], rj[4];
  if (lane == 0) { ri[wave] = pi; rj[wave] = pj; }
  __syncthreads();
  if (t == 0) {
    s_i[r] = ri[0] + ri[1] + ri[2] + ri[3];
    s_j[r] = rj[0] + rj[1] + rj[2] + rj[3];
  }
}

// ---------------- final antecedent scores ----------------
__global__ void out_kernel(const float* __restrict__ s_i, const float* __restrict__ s_j,
                           const float* __restrict__ ant_b, float* __restrict__ out) {
  int idx = blockIdx.x * 256 + threadIdx.x;
  if (idx >= KTOP * (KTOP + 1)) return;
  int i = idx / (KTOP + 1), c = idx % (KTOP + 1);
  float v;
  if (c == 0) v = 0.f;
  else {
    int j = c - 1;
    v = (j >= i) ? -10000.f : (s_i[i] + s_j[j] + ant_b[0]);
  }
  out[idx] = v;
}

extern "C" void kernel_launch(void* const* d_in, const int* in_sizes, int n_in,
                              void* d_out, int out_size, void* d_ws, size_t ws_size,
                              hipStream_t stream) {
  const float* x      = (const float*)d_in[0];
  const int*   edges  = (const int*)d_in[1];
  const float* gcn_W  = (const float*)d_in[2];
  const float* gcn_b  = (const float*)d_in[3];
  const float* attn_w = (const float*)d_in[4];
  // d_in[5] attn_b: softmax-shift invariant, unused
  const float* ms_W1  = (const float*)d_in[6];
  const float* ms_b1  = (const float*)d_in[7];
  const float* ms_W2  = (const float*)d_in[8];
  // d_in[9] ms_b2: constant shift, doesn't affect top-k order or output
  const float* ant_W  = (const float*)d_in[10];
  const float* ant_b  = (const float*)d_in[11];
  const int* starts   = (const int*)d_in[12];
  const int* ends     = (const int*)d_in[13];
  // d_in[14] topk = 409 (hardcoded; fixed by problem sizes)

  size_t off = 0;
  char* wsb = (char*)d_ws;
  auto alloc = [&](size_t bytes) -> void* {
    void* p = wsb + off;
    off += (bytes + 255) & ~(size_t)255;
    return p;
  };
  unsigned short* agg   = (unsigned short*)alloc((size_t)S_TOK * KGCN * 2);   // 78.6 MB
  unsigned short* Wt1   = (unsigned short*)alloc((size_t)H_DIM * KGCN * 2);   // 59.0 MB
  unsigned short* Wt2   = (unsigned short*)alloc((size_t)DDIM * DDIM * 2);    // 10.6 MB
  unsigned short* spanv = (unsigned short*)alloc((size_t)MPAD * DDIM * 2);    // 42.5 MB
  int* seg_count  = (int*)alloc(NSEG * 4);
  int* seg_off    = (int*)alloc((NSEG + 4) * 4);
  int* seg_cursor = (int*)alloc(NSEG * 4);
  int* sorted_src = (int*)alloc(NEDGE * 4);
  float* C1     = (float*)alloc((size_t)S_TOK * H_DIM * 4);
  float* emb    = (float*)alloc((size_t)S_TOK * H_DIM * 4);
  float* scores = (float*)alloc(MPAD * 4);
  int* topk_idx = (int*)alloc(512 * 4);
  float* s_i    = (float*)alloc(512 * 4);
  float* s_j    = (float*)alloc(512 * 4);
  (void)ws_size; (void)in_sizes; (void)n_in; (void)out_size;

  hipMemsetAsync(seg_count, 0, NSEG * 4, stream);
  hipMemsetAsync(seg_cursor, 0, NSEG * 4, stream);
  hipMemsetAsync(C1, 0, (size_t)S_TOK * H_DIM * 4, stream);
  hipMemsetAsync(scores, 0, MPAD * 4, stream);

  dim3 b256(256);
  transpose_conv<<<dim3(H_DIM / 32, KGCN / 32), b256, 0, stream>>>(gcn_W, Wt1, KGCN, H_DIM);
  transpose_conv<<<dim3(DDIM / 32, DDIM / 32), b256, 0, stream>>>(ms_W1, Wt2, DDIM, DDIM);
  edge_count<<<NEDGE / 256, b256, 0, stream>>>(edges, seg_count);
  scan_kernel<<<1, 1024, 0, stream>>>(seg_count, seg_off);
  edge_scatter<<<NEDGE / 256, b256, 0, stream>>>(edges, seg_off, seg_cursor, sorted_src);
  agg_kernel<<<NSEG / 4, b256, 0, stream>>>(x, seg_off, sorted_src, agg);
  // GEMM1: (1024 x 38400) @ (38400 x 768), split-K=24 (kChunk=1600)
  gemm_bf16<0><<<8 * 6 * 24, b256, 0, stream>>>((const __bf16*)agg, (const __bf16*)Wt1, C1,
                                                nullptr, nullptr, S_TOK, H_DIM, KGCN, 8, 6, 1600);
  emb_kernel<<<S_TOK, b256, 0, stream>>>(x, C1, seg_count, gcn_b, emb);
  span_kernel<<<NSPAN, b256, 0, stream>>>(emb, starts, ends, attn_w, spanv, NSPAN);
  // GEMM2: (9171 x 2304) @ (2304 x 2304) with fused relu(+b1)*W2 row-reduce epilogue
  gemm_bf16<1><<<72 * 18, b256, 0, stream>>>((const __bf16*)spanv, (const __bf16*)Wt2, scores,
                                             ms_b1, ms_W2, NSPAN, DDIM, DDIM, 72, 18, DDIM);
  topk_kernel<<<1, 1024, 0, stream>>>(scores, topk_idx);
  sij_kernel<<<KTOP, b256, 0, stream>>>(spanv, topk_idx, ant_W, s_i, s_j);
  out_kernel<<<(KTOP * (KTOP + 1) + 255) / 256, b256, 0, stream>>>(s_i, s_j, ant_b, (float*)d_out);
}